// Round 3
// baseline (15704.321 us; speedup 1.0000x reference)
//
#include <hip/hip_runtime.h>
#include <hip/hip_bf16.h>
#include <hip/hip_fp16.h>

// LSTM tagger: T=4096, V=50257, E=512, H=1024, TAGS=64
//
//   K1 prep:   bsum = b_ih + b_hh; init (tag16|fp16 h) slot buffers.
//   K2 gemm:   x_proj[T][4H] = emb[sentence] @ W_ih^T + bsum   (fp32 tiled)
//   K3 scan:   512 INDEPENDENT waves (128 WGs x 256 thr, no barriers/LDS).
//              Wave owns h[j0], h[j0+1]; W_hh slice in VGPRs (128 f/lane).
//              Per step: 1 asm block of 4x global_load_dwordx4 sc0 sc1 polls
//              all 1024 (tag|h) u32 slots; 16 tag checks; 128 FMA dot;
//              butterfly allreduce; lane-parallel activations; one relaxed
//              u64 atomic publishes both entries (tag rides with data).
//   K4 out:    tag_space = hs @ W_out^T + b_out; log_softmax over 64 tags.

#define T_LEN 4096
#define HID   1024
#define G4H   4096
#define EMBD  512
#define NTAGS 64
#define NWG_SCAN 128

typedef unsigned u32x4 __attribute__((ext_vector_type(4)));

__device__ __forceinline__ float fast_sig(float x) {
    return 1.f / (1.f + __expf(-x));
}
__device__ __forceinline__ float fast_tanh(float x) {
    x = fminf(15.f, fmaxf(-15.f, x));
    float e = __expf(2.f * x);
    return (e - 1.f) / (e + 1.f);
}
__device__ __forceinline__ float f16bits2f(unsigned b) {
    return __half2float(__ushort_as_half((unsigned short)(b & 0xFFFFu)));
}

__global__ void prep_kernel(const float* __restrict__ b_ih, const float* __restrict__ b_hh,
                            float* __restrict__ bsum, unsigned* __restrict__ slots) {
    int i = blockIdx.x * blockDim.x + threadIdx.x;
    int n = gridDim.x * blockDim.x;
    for (int k = i; k < G4H; k += n) bsum[k] = b_ih[k] + b_hh[k];
    for (int k = i; k < HID; k += n) {
        slots[k] = 0u;                 // parity 0: tag=0, h=fp16(0)
        slots[HID + k] = 0xFFFF0000u;  // parity 1: invalid tag
    }
}

// C[m,n] = sum_k emb[sent[m]][k] * W_ih[n][k] + bsum[n]; 64x64 tile per WG.
__global__ __launch_bounds__(256) void xproj_gemm(const int* __restrict__ sent,
                                                  const float* __restrict__ emb,
                                                  const float* __restrict__ W_ih,
                                                  const float* __restrict__ bsum,
                                                  float* __restrict__ xp) {
    __shared__ float As[32][68];
    __shared__ float Bs[32][68];
    const int tid = threadIdx.x;
    const int bx = blockIdx.x;  // n tile
    const int by = blockIdx.y;  // m tile
    const int tx = tid & 15, ty = tid >> 4;
    const int mrow = tid >> 2;     // 0..63
    const int kq = (tid & 3) * 8;  // 0,8,16,24

    float acc[4][4];
#pragma unroll
    for (int r = 0; r < 4; r++)
#pragma unroll
        for (int c = 0; c < 4; c++) acc[r][c] = 0.f;

    const int sid = sent[by * 64 + mrow];
    const float* arow = emb + (size_t)sid * EMBD;
    const float* brow = W_ih + (size_t)(bx * 64 + mrow) * EMBD;

    for (int kk = 0; kk < EMBD; kk += 32) {
        float4 a0 = *(const float4*)(arow + kk + kq);
        float4 a1 = *(const float4*)(arow + kk + kq + 4);
        float4 b0 = *(const float4*)(brow + kk + kq);
        float4 b1 = *(const float4*)(brow + kk + kq + 4);
        __syncthreads();
        const float* ap0 = (const float*)&a0;
        const float* ap1 = (const float*)&a1;
        const float* bp0 = (const float*)&b0;
        const float* bp1 = (const float*)&b1;
#pragma unroll
        for (int r = 0; r < 4; r++) {
            As[kq + r][mrow] = ap0[r];
            As[kq + 4 + r][mrow] = ap1[r];
            Bs[kq + r][mrow] = bp0[r];
            Bs[kq + 4 + r][mrow] = bp1[r];
        }
        __syncthreads();
#pragma unroll
        for (int k = 0; k < 32; k++) {
            float4 av = *(const float4*)&As[k][ty * 4];
            float4 bv = *(const float4*)&Bs[k][tx * 4];
            const float* ar = (const float*)&av;
            const float* br = (const float*)&bv;
#pragma unroll
            for (int r = 0; r < 4; r++)
#pragma unroll
                for (int c = 0; c < 4; c++) acc[r][c] = fmaf(ar[r], br[c], acc[r][c]);
        }
    }
    const int crow = by * 64 + ty * 4;
    const int ccol = bx * 64 + tx * 4;
    float bs[4];
#pragma unroll
    for (int c = 0; c < 4; c++) bs[c] = bsum[ccol + c];
#pragma unroll
    for (int r = 0; r < 4; r++) {
        float4 v;
        v.x = acc[r][0] + bs[0];
        v.y = acc[r][1] + bs[1];
        v.z = acc[r][2] + bs[2];
        v.w = acc[r][3] + bs[3];
        *(float4*)&xp[(size_t)(crow + r) * G4H + ccol] = v;
    }
}

// Persistent scan: 512 independent waves, 2 h-entries each, zero barriers.
// slots[par*HID + j] = (tag:16 | fp16(h):16), relaxed agent atomics only.
// Lane l owns k-indices {i*256 + l*4 + r : i<4, r<4} of the 1024-long dot.
__global__ __launch_bounds__(256, 1) void lstm_scan(const float* __restrict__ W_hh,
                                                    const float* __restrict__ xp,
                                                    unsigned* __restrict__ slots,
                                                    float* __restrict__ hs) {
    const int tid = threadIdx.x;
    const int g = blockIdx.x;
    const int w = tid >> 6;
    const int l = tid & 63;
    const int wave_id = g * 4 + w;  // 0..511
    const int j0 = wave_id * 2;     // owned entries j0, j0+1
    const int e_mine = l & 1;       // this lane finalizes entry j0+e_mine

    // wreg[e][q][i][r] = W_hh[q*HID + j0+e][i*256 + l*4 + r]
    float wreg[2][4][4][4];
#pragma unroll
    for (int e = 0; e < 2; e++)
#pragma unroll
        for (int q = 0; q < 4; q++) {
            const float* wr = W_hh + (size_t)(q * HID + j0 + e) * HID + l * 4;
#pragma unroll
            for (int i = 0; i < 4; i++) {
                float4 v = *(const float4*)(wr + i * 256);
                wreg[e][q][i][0] = v.x;
                wreg[e][q][i][1] = v.y;
                wreg[e][q][i][2] = v.z;
                wreg[e][q][i][3] = v.w;
            }
        }

    float c = 0.f;  // cell state for entry j0+e_mine (valid on every lane)
    for (int s = 1; s <= T_LEN; ++s) {
        const int t = s - 1;
        const unsigned need = (unsigned)t;

        // x_proj gate biases for this lane's entry (broadcast-coalesced)
        float xpv[4];
#pragma unroll
        for (int q = 0; q < 4; q++)
            xpv[q] = xp[(size_t)t * G4H + q * HID + j0 + e_mine];

        // poll ALL 1024 slots: 4 x dwordx4, one MALL round trip per iter
        const unsigned* pb = slots + ((t & 1) << 10);
        const unsigned* p0 = pb + 0 * 256 + l * 4;
        const unsigned* p1 = pb + 1 * 256 + l * 4;
        const unsigned* p2 = pb + 2 * 256 + l * 4;
        const unsigned* p3 = pb + 3 * 256 + l * 4;
        u32x4 u0, u1, u2, u3;
        for (;;) {
            asm volatile(
                "global_load_dwordx4 %0, %4, off sc0 sc1\n\t"
                "global_load_dwordx4 %1, %5, off sc0 sc1\n\t"
                "global_load_dwordx4 %2, %6, off sc0 sc1\n\t"
                "global_load_dwordx4 %3, %7, off sc0 sc1\n\t"
                "s_waitcnt vmcnt(0)"
                : "=v"(u0), "=v"(u1), "=v"(u2), "=v"(u3)
                : "v"(p0), "v"(p1), "v"(p2), "v"(p3)
                : "memory");
            unsigned m;
            m  = (u0.x >> 16) ^ need; m |= (u0.y >> 16) ^ need;
            m |= (u0.z >> 16) ^ need; m |= (u0.w >> 16) ^ need;
            m |= (u1.x >> 16) ^ need; m |= (u1.y >> 16) ^ need;
            m |= (u1.z >> 16) ^ need; m |= (u1.w >> 16) ^ need;
            m |= (u2.x >> 16) ^ need; m |= (u2.y >> 16) ^ need;
            m |= (u2.z >> 16) ^ need; m |= (u2.w >> 16) ^ need;
            m |= (u3.x >> 16) ^ need; m |= (u3.y >> 16) ^ need;
            m |= (u3.z >> 16) ^ need; m |= (u3.w >> 16) ^ need;
            if (__all(m == 0u)) break;
            __builtin_amdgcn_s_sleep(1);
        }

        // unpack fp16 h -> fp32
        float hk[4][4];
        hk[0][0] = f16bits2f(u0.x); hk[0][1] = f16bits2f(u0.y);
        hk[0][2] = f16bits2f(u0.z); hk[0][3] = f16bits2f(u0.w);
        hk[1][0] = f16bits2f(u1.x); hk[1][1] = f16bits2f(u1.y);
        hk[1][2] = f16bits2f(u1.z); hk[1][3] = f16bits2f(u1.w);
        hk[2][0] = f16bits2f(u2.x); hk[2][1] = f16bits2f(u2.y);
        hk[2][2] = f16bits2f(u2.z); hk[2][3] = f16bits2f(u2.w);
        hk[3][0] = f16bits2f(u3.x); hk[3][1] = f16bits2f(u3.y);
        hk[3][2] = f16bits2f(u3.z); hk[3][3] = f16bits2f(u3.w);

        // partial dots: 128 FMA/lane
        float a[2][4];
#pragma unroll
        for (int e = 0; e < 2; e++)
#pragma unroll
            for (int q = 0; q < 4; q++) a[e][q] = 0.f;
#pragma unroll
        for (int i = 0; i < 4; i++)
#pragma unroll
            for (int r = 0; r < 4; r++) {
                float hv = hk[i][r];
#pragma unroll
                for (int e = 0; e < 2; e++)
#pragma unroll
                    for (int q = 0; q < 4; q++)
                        a[e][q] = fmaf(wreg[e][q][i][r], hv, a[e][q]);
            }
        // butterfly allreduce (all lanes end with full sums)
#pragma unroll
        for (int m = 32; m >= 1; m >>= 1)
#pragma unroll
            for (int e = 0; e < 2; e++)
#pragma unroll
                for (int q = 0; q < 4; q++) a[e][q] += __shfl_xor(a[e][q], m);

        // every lane finalizes its entry (e_mine) -- no serial tail
        float ge[4];
#pragma unroll
        for (int q = 0; q < 4; q++) ge[q] = e_mine ? a[1][q] : a[0][q];
        float si = fast_sig(ge[0] + xpv[0]);
        float sf = fast_sig(ge[1] + xpv[1]);
        float tg = fast_tanh(ge[2] + xpv[2]);
        float so = fast_sig(ge[3] + xpv[3]);
        c = sf * c + si * tg;
        float hval = so * fast_tanh(c);

        unsigned pk = ((unsigned)s << 16) |
                      (unsigned)__half_as_ushort(__float2half(hval));
        unsigned pk0 = __shfl(pk, 0);
        unsigned pk1 = __shfl(pk, 1);
        if (l == 0) {
            unsigned long long pv =
                (unsigned long long)pk0 | ((unsigned long long)pk1 << 32);
            __hip_atomic_store((unsigned long long*)(slots + ((s & 1) << 10) + j0),
                               pv, __ATOMIC_RELAXED, __HIP_MEMORY_SCOPE_AGENT);
        }
        if (l < 2) hs[(size_t)t * HID + j0 + l] = hval;  // fp32 h for output GEMM
    }
}

// tag_space = hs @ W_out^T + b_out; log_softmax per row. 8 rows per WG, 1 wave.
__global__ __launch_bounds__(64) void out_kernel(const float* __restrict__ hs,
                                                 const float* __restrict__ W_out,
                                                 const float* __restrict__ b_out,
                                                 float* __restrict__ out) {
    __shared__ float hl[8 * HID];
    const int l = threadIdx.x;
    const int b = blockIdx.x;  // 512 blocks
    const float* hr = hs + (size_t)b * 8 * HID;
#pragma unroll
    for (int jj = 0; jj < 32; jj++) {
        int f4 = l + 64 * jj;
        ((float4*)hl)[f4] = ((const float4*)hr)[f4];
    }
    __syncthreads();
    float acc[8];
#pragma unroll
    for (int r = 0; r < 8; r++) acc[r] = 0.f;
    const float* wrow = W_out + (size_t)l * HID;
    for (int e = 0; e < HID; e += 4) {
        float4 wv = *(const float4*)(wrow + e);
#pragma unroll
        for (int r = 0; r < 8; r++) {
            float4 hv = *(const float4*)&hl[r * HID + e];
            acc[r] += wv.x * hv.x + wv.y * hv.y + wv.z * hv.z + wv.w * hv.w;
        }
    }
    const float bo = b_out[l];
#pragma unroll
    for (int r = 0; r < 8; r++) {
        float v = acc[r] + bo;
        float mx = v;
#pragma unroll
        for (int m = 32; m >= 1; m >>= 1) mx = fmaxf(mx, __shfl_xor(mx, m));
        float ex = __expf(v - mx);
        float sm = ex;
#pragma unroll
        for (int m = 32; m >= 1; m >>= 1) sm += __shfl_xor(sm, m);
        out[(size_t)(b * 8 + r) * NTAGS + l] = v - mx - __logf(sm);
    }
}

extern "C" void kernel_launch(void* const* d_in, const int* in_sizes, int n_in,
                              void* d_out, int out_size, void* d_ws, size_t ws_size,
                              hipStream_t stream) {
    const int* sent = (const int*)d_in[0];
    const float* emb = (const float*)d_in[1];
    const float* W_ih = (const float*)d_in[2];
    const float* W_hh = (const float*)d_in[3];
    const float* b_ih = (const float*)d_in[4];
    const float* b_hh = (const float*)d_in[5];
    const float* W_out = (const float*)d_in[6];
    const float* b_out = (const float*)d_in[7];
    float* out = (float*)d_out;

    char* ws = (char*)d_ws;
    float* xp = (float*)ws;                                   // 64 MB
    float* hs = (float*)(ws + ((size_t)64 << 20));            // 16 MB
    unsigned* slots = (unsigned*)(ws + ((size_t)80 << 20));   // 8 KB
    float* bsum = (float*)(ws + ((size_t)80 << 20) + 32768);  // 16 KB

    prep_kernel<<<16, 256, 0, stream>>>(b_ih, b_hh, bsum, slots);
    dim3 g(G4H / 64, T_LEN / 64);
    xproj_gemm<<<g, 256, 0, stream>>>(sent, emb, W_ih, bsum, xp);
    lstm_scan<<<NWG_SCAN, 256, 0, stream>>>(W_hh, xp, slots, hs);
    out_kernel<<<512, 64, 0, stream>>>(hs, W_out, b_out, out);
}

// Round 6
// 11292.109 us; speedup vs baseline: 1.3907x; 1.3907x over previous
//
#include <hip/hip_runtime.h>
#include <hip/hip_bf16.h>
#include <hip/hip_fp16.h>

// LSTM tagger: T=4096, V=50257, E=512, H=1024, TAGS=64
//
//   K1 prep:   bsum=b_ih+b_hh; init fused (tag16|h16) slot replicas.
//   K2 gemm:   x_proj[T][4H] = emb[sentence] @ W_ih^T + bsum (fp32 tiled).
//   K3 scan:   32 WGs x 512 thr (256 waves, 4 h-entries each).
//              Publish: atomicExch of (s<<16|fp16 h) into 8 staggered
//              replicas (RMW commits at MALL -- no write-back laziness).
//              Detect: ONE poller wave per WG polls its replica (4KB) with
//              proven sc0 sc1 loads; relays h to 7 sibling waves via LDS.
//              Compute: 32 chained mfma_f32_16x16x32_f16, W_hh fp16 in
//              VGPRs, B = h broadcast -> col-dup C, lane-parallel act.
//              All spins budget-bounded (deadlock -> fast wrong answer).
//   K4 out:    tag_space = hs @ W_out^T + b_out; log_softmax over 64 tags.

#define T_LEN 4096
#define HID   1024
#define G4H   4096
#define EMBD  512
#define NTAGS 64
#define NREP  8
#define RSTRIDE_U32 2112  // per-replica stride (2 parities * 1024 + 64 pad)
#define NWG_SCAN 32

typedef unsigned u32x4 __attribute__((ext_vector_type(4)));
typedef float    f32x4 __attribute__((ext_vector_type(4)));
typedef _Float16 f16x8 __attribute__((ext_vector_type(8)));

__device__ __forceinline__ float fast_sig(float x) { return 1.f / (1.f + __expf(-x)); }
__device__ __forceinline__ float fast_tanh(float x) {
  x = fminf(15.f, fmaxf(-15.f, x));
  float e = __expf(2.f * x);
  return (e - 1.f) / (e + 1.f);
}

__global__ void prep_kernel(const float* __restrict__ b_ih, const float* __restrict__ b_hh,
                            float* __restrict__ bsum, unsigned* __restrict__ slots) {
  int i = blockIdx.x * blockDim.x + threadIdx.x;
  int n = gridDim.x * blockDim.x;
  for (int k = i; k < G4H; k += n) bsum[k] = b_ih[k] + b_hh[k];
  for (int k = i; k < NREP * RSTRIDE_U32; k += n) {
    int within = k % RSTRIDE_U32;
    unsigned v = (within < 1024) ? 0u                     // parity0: tag0, h=0
               : (within < 2048) ? 0xFFFF0000u            // parity1: invalid tag
                                 : 0u;                    // pad
    slots[k] = v;
  }
}

// C[m,n] = sum_k emb[sent[m]][k] * W_ih[n][k] + bsum[n]; 64x64 tile per WG.
__global__ __launch_bounds__(256) void xproj_gemm(const int* __restrict__ sent,
                                                  const float* __restrict__ emb,
                                                  const float* __restrict__ W_ih,
                                                  const float* __restrict__ bsum,
                                                  float* __restrict__ xp) {
  __shared__ float As[32][68];
  __shared__ float Bs[32][68];
  const int tid = threadIdx.x;
  const int bx = blockIdx.x, by = blockIdx.y;
  const int tx = tid & 15, ty = tid >> 4;
  const int mrow = tid >> 2;
  const int kq = (tid & 3) * 8;

  float acc[4][4];
#pragma unroll
  for (int r = 0; r < 4; r++)
#pragma unroll
    for (int c = 0; c < 4; c++) acc[r][c] = 0.f;

  const int sid = sent[by * 64 + mrow];
  const float* arow = emb + (size_t)sid * EMBD;
  const float* brow = W_ih + (size_t)(bx * 64 + mrow) * EMBD;

  for (int kk = 0; kk < EMBD; kk += 32) {
    float4 a0 = *(const float4*)(arow + kk + kq);
    float4 a1 = *(const float4*)(arow + kk + kq + 4);
    float4 b0 = *(const float4*)(brow + kk + kq);
    float4 b1 = *(const float4*)(brow + kk + kq + 4);
    __syncthreads();
    const float* ap0 = (const float*)&a0;
    const float* ap1 = (const float*)&a1;
    const float* bp0 = (const float*)&b0;
    const float* bp1 = (const float*)&b1;
#pragma unroll
    for (int r = 0; r < 4; r++) {
      As[kq + r][mrow] = ap0[r];
      As[kq + 4 + r][mrow] = ap1[r];
      Bs[kq + r][mrow] = bp0[r];
      Bs[kq + 4 + r][mrow] = bp1[r];
    }
    __syncthreads();
#pragma unroll
    for (int k = 0; k < 32; k++) {
      float4 av = *(const float4*)&As[k][ty * 4];
      float4 bv = *(const float4*)&Bs[k][tx * 4];
      const float* ar = (const float*)&av;
      const float* br = (const float*)&bv;
#pragma unroll
      for (int r = 0; r < 4; r++)
#pragma unroll
        for (int c = 0; c < 4; c++) acc[r][c] = fmaf(ar[r], br[c], acc[r][c]);
    }
  }
  const int crow = by * 64 + ty * 4;
  const int ccol = bx * 64 + tx * 4;
  float bs[4];
#pragma unroll
  for (int c = 0; c < 4; c++) bs[c] = bsum[ccol + c];
#pragma unroll
  for (int r = 0; r < 4; r++) {
    float4 v;
    v.x = acc[r][0] + bs[0];
    v.y = acc[r][1] + bs[1];
    v.z = acc[r][2] + bs[2];
    v.w = acc[r][3] + bs[3];
    *(float4*)&xp[(size_t)(crow + r) * G4H + ccol] = v;
  }
}

#define MFMA16(A, B, C) __builtin_amdgcn_mfma_f32_16x16x32_f16((A), (B), (C), 0, 0, 0)

// Scan: 32 WGs x 8 waves. Wave (g,w) owns entries e0=(g*8+w)*4 .. +4.
// Lane roles: kb = l>>4 (entry within wave / B k-chunk), m = l&15 (A row).
__global__ __launch_bounds__(512, 2) void lstm_scan(const float* __restrict__ W_hh,
                                                    const float* __restrict__ xp,
                                                    unsigned* __restrict__ slots,
                                                    float* __restrict__ hs) {
  __shared__ _Float16 h_lds[2][HID];
  __shared__ int wgstep;
  const int tid = threadIdx.x;
  const int g = blockIdx.x;
  const int w = tid >> 6, l = tid & 63;
  const int kb = l >> 4, m = l & 15;
  const int qa = m & 3, ra = m >> 2;
  const int e0 = (g * 8 + w) * 4;

  if (tid == 0) wgstep = 0;
  __syncthreads();
  volatile int* wgs = &wgstep;

  // A frags: lane l holds A row m, k = k0*32 + kb*8 + j.
  // A row r must be W_hh row (r&3)*HID + e0 + (r>>2)  (C row r = gate r&3 of
  // entry e0 + (r>>2); C layout: row=(l>>4)*4+reg, col=l&15 -> col-dup).
  f16x8 afrag[32];
  {
    const float* wr = W_hh + (size_t)(qa * HID + e0 + ra) * HID + kb * 8;
#pragma unroll
    for (int k0 = 0; k0 < 32; k0++) {
      float4 lo = *(const float4*)(wr + k0 * 32);
      float4 hi = *(const float4*)(wr + k0 * 32 + 4);
      f16x8 a;
      a[0] = (_Float16)lo.x; a[1] = (_Float16)lo.y;
      a[2] = (_Float16)lo.z; a[3] = (_Float16)lo.w;
      a[4] = (_Float16)hi.x; a[5] = (_Float16)hi.y;
      a[6] = (_Float16)hi.z; a[7] = (_Float16)hi.w;
      afrag[k0] = a;
    }
  }

  const unsigned* pollbase = slots + (g & 7) * RSTRIDE_U32 + l * 4;  // poller only
  unsigned* pubbase = slots + (l >> 2) * RSTRIDE_U32 + e0 + (l & 3); // lanes <32

  float cst = 0.f;
  int pbud = 1 << 22;   // total poll-iteration budget (deadlock -> fast exit)
  int sbud = 1 << 25;   // total LDS-spin budget
  for (int s = 1; s <= T_LEN; ++s) {
    const int t = s - 1;
    const int p = t & 1;
    const unsigned tt = (unsigned)t;

    // per-lane x_proj gate biases for entry e0+kb (issued before the wait)
    float xpv0 = xp[(size_t)t * G4H + 0 * HID + e0 + kb];
    float xpv1 = xp[(size_t)t * G4H + 1 * HID + e0 + kb];
    float xpv2 = xp[(size_t)t * G4H + 2 * HID + e0 + kb];
    float xpv3 = xp[(size_t)t * G4H + 3 * HID + e0 + kb];

    if (w == 0) {
      // poller: fetch all 1024 fused slots of replica g&7, parity p
      const unsigned* pp = pollbase + p * HID;
      u32x4 u0, u1, u2, u3;
      for (;;) {
        asm volatile(
            "global_load_dwordx4 %0, %4, off sc0 sc1\n\t"
            "global_load_dwordx4 %1, %4, off offset:1024 sc0 sc1\n\t"
            "global_load_dwordx4 %2, %4, off offset:2048 sc0 sc1\n\t"
            "global_load_dwordx4 %3, %4, off offset:3072 sc0 sc1\n\t"
            "s_waitcnt vmcnt(0)"
            : "=&v"(u0), "=&v"(u1), "=&v"(u2), "=&v"(u3)
            : "v"(pp) : "memory");
        unsigned mm;
        mm  = (u0.x >> 16) ^ tt; mm |= (u0.y >> 16) ^ tt;
        mm |= (u0.z >> 16) ^ tt; mm |= (u0.w >> 16) ^ tt;
        mm |= (u1.x >> 16) ^ tt; mm |= (u1.y >> 16) ^ tt;
        mm |= (u1.z >> 16) ^ tt; mm |= (u1.w >> 16) ^ tt;
        mm |= (u2.x >> 16) ^ tt; mm |= (u2.y >> 16) ^ tt;
        mm |= (u2.z >> 16) ^ tt; mm |= (u2.w >> 16) ^ tt;
        mm |= (u3.x >> 16) ^ tt; mm |= (u3.y >> 16) ^ tt;
        mm |= (u3.z >> 16) ^ tt; mm |= (u3.w >> 16) ^ tt;
        if (__all(mm == 0u)) break;
        if (--pbud <= 0) break;
        __builtin_amdgcn_s_sleep(1);
      }
      // relay: write fp16 h into LDS parity p (entries c*256 + l*4 + r)
      uint2 v0 = { (u0.x & 0xFFFFu) | (u0.y << 16), (u0.z & 0xFFFFu) | (u0.w << 16) };
      uint2 v1 = { (u1.x & 0xFFFFu) | (u1.y << 16), (u1.z & 0xFFFFu) | (u1.w << 16) };
      uint2 v2 = { (u2.x & 0xFFFFu) | (u2.y << 16), (u2.z & 0xFFFFu) | (u2.w << 16) };
      uint2 v3 = { (u3.x & 0xFFFFu) | (u3.y << 16), (u3.z & 0xFFFFu) | (u3.w << 16) };
      *(uint2*)&h_lds[p][0 * 256 + l * 4] = v0;
      *(uint2*)&h_lds[p][1 * 256 + l * 4] = v1;
      *(uint2*)&h_lds[p][2 * 256 + l * 4] = v2;
      *(uint2*)&h_lds[p][3 * 256 + l * 4] = v3;
      asm volatile("s_waitcnt lgkmcnt(0)" ::: "memory");
      __builtin_amdgcn_sched_barrier(0);
      if (l == 0) *wgs = s;
    } else {
      while (*wgs < s) {
        if (--sbud <= 0) break;
      }
      __builtin_amdgcn_sched_barrier(0);
    }

    // gates via 32 chained MFMAs: B = h[k0*32 + kb*8 .. +8] (broadcast cols)
    const _Float16* hb = &h_lds[p][kb * 8];
    f32x4 acc0 = {0.f, 0.f, 0.f, 0.f}, acc1 = {0.f, 0.f, 0.f, 0.f};
#pragma unroll
    for (int k0 = 0; k0 < 32; k0 += 2) {
      f16x8 b0 = *(const f16x8*)(hb + k0 * 32);
      f16x8 b1 = *(const f16x8*)(hb + (k0 + 1) * 32);
      acc0 = MFMA16(afrag[k0], b0, acc0);
      acc1 = MFMA16(afrag[k0 + 1], b1, acc1);
    }
    f32x4 gsum = acc0 + acc1;

    // every lane finalizes entry e0+kb (16-way redundant, deterministic)
    float si = fast_sig(gsum[0] + xpv0);
    float sf = fast_sig(gsum[1] + xpv1);
    float tg = fast_tanh(gsum[2] + xpv2);
    float so = fast_sig(gsum[3] + xpv3);
    cst = sf * cst + si * tg;
    float hval = so * fast_tanh(cst);

    // publish: fused (s<<16 | fp16 h) via atomicExch to 8 replicas
    unsigned pk = ((unsigned)s << 16) |
                  (unsigned)__half_as_ushort(__float2half(hval));
    unsigned pks = (unsigned)__shfl((int)pk, (l & 3) << 4);
    if (l < 32) atomicExch(pubbase + (s & 1) * HID, pks);
    if (m == 0) hs[(size_t)t * HID + e0 + kb] = hval;
  }
}

// tag_space = hs @ W_out^T + b_out; log_softmax per row. 8 rows per WG, 1 wave.
__global__ __launch_bounds__(64) void out_kernel(const float* __restrict__ hs,
                                                 const float* __restrict__ W_out,
                                                 const float* __restrict__ b_out,
                                                 float* __restrict__ out) {
  __shared__ float hl[8 * HID];
  const int l = threadIdx.x;
  const int b = blockIdx.x;
  const float* hr = hs + (size_t)b * 8 * HID;
#pragma unroll
  for (int jj = 0; jj < 32; jj++) {
    int f4 = l + 64 * jj;
    ((float4*)hl)[f4] = ((const float4*)hr)[f4];
  }
  __syncthreads();
  float acc[8];
#pragma unroll
  for (int r = 0; r < 8; r++) acc[r] = 0.f;
  const float* wrow = W_out + (size_t)l * HID;
  for (int e = 0; e < HID; e += 4) {
    float4 wv = *(const float4*)(wrow + e);
#pragma unroll
    for (int r = 0; r < 8; r++) {
      float4 hv = *(const float4*)&hl[r * HID + e];
      acc[r] += wv.x * hv.x + wv.y * hv.y + wv.z * hv.z + wv.w * hv.w;
    }
  }
  const float bo = b_out[l];
#pragma unroll
  for (int r = 0; r < 8; r++) {
    float v = acc[r] + bo;
    float mx = v;
#pragma unroll
    for (int mm = 32; mm >= 1; mm >>= 1) mx = fmaxf(mx, __shfl_xor(mx, mm));
    float ex = __expf(v - mx);
    float sm = ex;
#pragma unroll
    for (int mm = 32; mm >= 1; mm >>= 1) sm += __shfl_xor(sm, mm);
    out[(size_t)(b * 8 + r) * NTAGS + l] = v - mx - __logf(sm);
  }
}

extern "C" void kernel_launch(void* const* d_in, const int* in_sizes, int n_in,
                              void* d_out, int out_size, void* d_ws, size_t ws_size,
                              hipStream_t stream) {
  const int* sent = (const int*)d_in[0];
  const float* emb = (const float*)d_in[1];
  const float* W_ih = (const float*)d_in[2];
  const float* W_hh = (const float*)d_in[3];
  const float* b_ih = (const float*)d_in[4];
  const float* b_hh = (const float*)d_in[5];
  const float* W_out = (const float*)d_in[6];
  const float* b_out = (const float*)d_in[7];
  float* out = (float*)d_out;

  char* ws = (char*)d_ws;
  float* xp = (float*)ws;                                    // 64 MB
  float* hs = (float*)(ws + ((size_t)64 << 20));             // 16 MB
  unsigned* slots = (unsigned*)(ws + ((size_t)80 << 20));    // 8 * 8448 B
  float* bsum = (float*)(ws + ((size_t)80 << 20) + 131072);  // 16 KB

  prep_kernel<<<16, 256, 0, stream>>>(b_ih, b_hh, bsum, slots);
  dim3 grid(G4H / 64, T_LEN / 64);
  xproj_gemm<<<grid, 256, 0, stream>>>(sent, emb, W_ih, bsum, xp);
  lstm_scan<<<NWG_SCAN, 512, 0, stream>>>(W_hh, xp, slots, hs);
  out_kernel<<<512, 64, 0, stream>>>(hs, W_out, b_out, out);
}

// Round 7
// 11285.232 us; speedup vs baseline: 1.3916x; 1.0006x over previous
//
#include <hip/hip_runtime.h>
#include <hip/hip_bf16.h>
#include <hip/hip_fp16.h>

// LSTM tagger: T=4096, V=50257, E=512, H=1024, TAGS=64
//
//   K1 prep:   bsum=b_ih+b_hh; init fused (tag16|h16) u64-pair slot replicas.
//   K2 gemm:   x_proj[T][4H] = emb[sentence] @ W_ih^T + bsum (fp32 tiled).
//   K3 scan:   256 INDEPENDENT waves (256 WGs x 64 thr, no intra-WG sync).
//              Wave owns entries e0=wid*4..+4. Per step: poll replica
//              (wid&3) with 4x dwordx4 sc0 sc1 (returns tag+data fused);
//              pack fp16 h into PRIVATE 2KB LDS (layout transform only);
//              32 chained mfma_f32_16x16x32_f16 (W_hh fp16 resident in
//              VGPRs, B = h broadcast -> col-dup C); lane-parallel
//              activations; publish 2 u64 atomicExch x 4 replicas
//              (lanes 0-7, RMW commits at coherence point).
//              All spins budget-bounded.
//   K4 out:    tag_space = hs @ W_out^T + b_out; log_softmax over 64 tags.

#define T_LEN 4096
#define HID   1024
#define G4H   4096
#define EMBD  512
#define NTAGS 64
#define NREP  4
#define RSTRIDE_U32 2112   // per-replica stride in u32 (2 parities*1024 + 64 pad)
#define RSTRIDE_B   8448   // bytes
#define NWG_SCAN 256

typedef unsigned u32x4 __attribute__((ext_vector_type(4)));
typedef float    f32x4 __attribute__((ext_vector_type(4)));
typedef _Float16 f16x8 __attribute__((ext_vector_type(8)));

__device__ __forceinline__ float fast_sig(float x) { return 1.f / (1.f + __expf(-x)); }
__device__ __forceinline__ float fast_tanh(float x) {
  x = fminf(15.f, fmaxf(-15.f, x));
  float e = __expf(2.f * x);
  return (e - 1.f) / (e + 1.f);
}

__global__ void prep_kernel(const float* __restrict__ b_ih, const float* __restrict__ b_hh,
                            float* __restrict__ bsum, unsigned* __restrict__ slots) {
  int i = blockIdx.x * blockDim.x + threadIdx.x;
  int n = gridDim.x * blockDim.x;
  for (int k = i; k < G4H; k += n) bsum[k] = b_ih[k] + b_hh[k];
  for (int k = i; k < NREP * RSTRIDE_U32; k += n) {
    int within = k % RSTRIDE_U32;
    unsigned v = (within < 1024) ? 0u            // parity0: tag=0, h=fp16(0)
               : (within < 2048) ? 0xFFFF0000u   // parity1: invalid tag
                                 : 0u;           // pad
    slots[k] = v;
  }
}

// C[m,n] = sum_k emb[sent[m]][k] * W_ih[n][k] + bsum[n]; 64x64 tile per WG.
__global__ __launch_bounds__(256) void xproj_gemm(const int* __restrict__ sent,
                                                  const float* __restrict__ emb,
                                                  const float* __restrict__ W_ih,
                                                  const float* __restrict__ bsum,
                                                  float* __restrict__ xp) {
  __shared__ float As[32][68];
  __shared__ float Bs[32][68];
  const int tid = threadIdx.x;
  const int bx = blockIdx.x, by = blockIdx.y;
  const int tx = tid & 15, ty = tid >> 4;
  const int mrow = tid >> 2;
  const int kq = (tid & 3) * 8;

  float acc[4][4];
#pragma unroll
  for (int r = 0; r < 4; r++)
#pragma unroll
    for (int c = 0; c < 4; c++) acc[r][c] = 0.f;

  const int sid = sent[by * 64 + mrow];
  const float* arow = emb + (size_t)sid * EMBD;
  const float* brow = W_ih + (size_t)(bx * 64 + mrow) * EMBD;

  for (int kk = 0; kk < EMBD; kk += 32) {
    float4 a0 = *(const float4*)(arow + kk + kq);
    float4 a1 = *(const float4*)(arow + kk + kq + 4);
    float4 b0 = *(const float4*)(brow + kk + kq);
    float4 b1 = *(const float4*)(brow + kk + kq + 4);
    __syncthreads();
    const float* ap0 = (const float*)&a0;
    const float* ap1 = (const float*)&a1;
    const float* bp0 = (const float*)&b0;
    const float* bp1 = (const float*)&b1;
#pragma unroll
    for (int r = 0; r < 4; r++) {
      As[kq + r][mrow] = ap0[r];
      As[kq + 4 + r][mrow] = ap1[r];
      Bs[kq + r][mrow] = bp0[r];
      Bs[kq + 4 + r][mrow] = bp1[r];
    }
    __syncthreads();
#pragma unroll
    for (int k = 0; k < 32; k++) {
      float4 av = *(const float4*)&As[k][ty * 4];
      float4 bv = *(const float4*)&Bs[k][tx * 4];
      const float* ar = (const float*)&av;
      const float* br = (const float*)&bv;
#pragma unroll
      for (int r = 0; r < 4; r++)
#pragma unroll
        for (int c = 0; c < 4; c++) acc[r][c] = fmaf(ar[r], br[c], acc[r][c]);
    }
  }
  const int crow = by * 64 + ty * 4;
  const int ccol = bx * 64 + tx * 4;
  float bs[4];
#pragma unroll
  for (int c = 0; c < 4; c++) bs[c] = bsum[ccol + c];
#pragma unroll
  for (int r = 0; r < 4; r++) {
    float4 v;
    v.x = acc[r][0] + bs[0];
    v.y = acc[r][1] + bs[1];
    v.z = acc[r][2] + bs[2];
    v.w = acc[r][3] + bs[3];
    *(float4*)&xp[(size_t)(crow + r) * G4H + ccol] = v;
  }
}

#define MFMA16(A, B, C) __builtin_amdgcn_mfma_f32_16x16x32_f16((A), (B), (C), 0, 0, 0)

// Scan: 256 WGs x 1 wave, entries e0=wid*4..+4, fully independent.
// Lane roles: kb = l>>4 (entry / C row-block / B k-subchunk), m = l&15 (A row).
__global__ __launch_bounds__(64, 1) void lstm_scan(const float* __restrict__ W_hh,
                                                   const float* __restrict__ xp,
                                                   unsigned* __restrict__ slots,
                                                   float* __restrict__ hs) {
  __shared__ _Float16 h_lds[HID];  // private per-wave staging (layout transform)
  const int l = threadIdx.x;
  const int wid = blockIdx.x;
  const int kb = l >> 4, m = l & 15;
  const int qa = m & 3, ra = m >> 2;
  const int e0 = wid * 4;

  // A frags: lane l = A row m = W_hh row qa*HID + e0+ra; k = k0*32 + kb*8 + j.
  // C layout (verified R6): row=(l>>4)*4+reg -> gate reg of entry e0+kb, col dup.
  f16x8 afrag[32];
  {
    const float* wr = W_hh + (size_t)(qa * HID + e0 + ra) * HID + kb * 8;
#pragma unroll
    for (int k0 = 0; k0 < 32; k0++) {
      float4 lo = *(const float4*)(wr + k0 * 32);
      float4 hi = *(const float4*)(wr + k0 * 32 + 4);
      f16x8 a;
      a[0] = (_Float16)lo.x; a[1] = (_Float16)lo.y;
      a[2] = (_Float16)lo.z; a[3] = (_Float16)lo.w;
      a[4] = (_Float16)hi.x; a[5] = (_Float16)hi.y;
      a[6] = (_Float16)hi.z; a[7] = (_Float16)hi.w;
      afrag[k0] = a;
    }
  }

  const char* pollbase = (const char*)slots + (wid & 3) * RSTRIDE_B + (size_t)l * 64;

  float cst = 0.f;
  int pbud = 1 << 21;  // total poll budget: deadlock -> fast wrong answer
  for (int s = 1; s <= T_LEN; ++s) {
    const int t = s - 1;
    const int p = t & 1;
    const unsigned tt = (unsigned)t;

    // force-issue x_proj gate loads (ride under poll; drained by poll's vmcnt(0))
    const float* xb = xp + (size_t)t * G4H + e0 + kb;
    float xpv0, xpv1, xpv2, xpv3;
    asm volatile(
        "global_load_dword %0, %4, off\n\t"
        "global_load_dword %1, %5, off\n\t"
        "global_load_dword %2, %6, off\n\t"
        "global_load_dword %3, %7, off"
        : "=&v"(xpv0), "=&v"(xpv1), "=&v"(xpv2), "=&v"(xpv3)
        : "v"(xb), "v"(xb + HID), "v"(xb + 2 * HID), "v"(xb + 3 * HID));

    // poll all 512 u64 slots (each u32 component is one fused tag|h slot)
    const char* pp = pollbase + p * 4096;
    u32x4 u0, u1, u2, u3;
    for (;;) {
      asm volatile(
          "global_load_dwordx4 %0, %4, off sc0 sc1\n\t"
          "global_load_dwordx4 %1, %4, off offset:16 sc0 sc1\n\t"
          "global_load_dwordx4 %2, %4, off offset:32 sc0 sc1\n\t"
          "global_load_dwordx4 %3, %4, off offset:48 sc0 sc1\n\t"
          "s_waitcnt vmcnt(0)"
          : "=&v"(u0), "=&v"(u1), "=&v"(u2), "=&v"(u3)
          : "v"(pp) : "memory");
      unsigned mm;
      mm  = (u0.x >> 16) ^ tt; mm |= (u0.y >> 16) ^ tt;
      mm |= (u0.z >> 16) ^ tt; mm |= (u0.w >> 16) ^ tt;
      mm |= (u1.x >> 16) ^ tt; mm |= (u1.y >> 16) ^ tt;
      mm |= (u1.z >> 16) ^ tt; mm |= (u1.w >> 16) ^ tt;
      mm |= (u2.x >> 16) ^ tt; mm |= (u2.y >> 16) ^ tt;
      mm |= (u2.z >> 16) ^ tt; mm |= (u2.w >> 16) ^ tt;
      mm |= (u3.x >> 16) ^ tt; mm |= (u3.y >> 16) ^ tt;
      mm |= (u3.z >> 16) ^ tt; mm |= (u3.w >> 16) ^ tt;
      if (__all(mm == 0u)) break;
      if (--pbud <= 0) break;
    }

    // pack fp16 h into private LDS: lane l holds entries [l*16, l*16+16)
    u32x4 w0 = { (u0.x & 0xFFFFu) | (u0.y << 16), (u0.z & 0xFFFFu) | (u0.w << 16),
                 (u1.x & 0xFFFFu) | (u1.y << 16), (u1.z & 0xFFFFu) | (u1.w << 16) };
    u32x4 w1 = { (u2.x & 0xFFFFu) | (u2.y << 16), (u2.z & 0xFFFFu) | (u2.w << 16),
                 (u3.x & 0xFFFFu) | (u3.y << 16), (u3.z & 0xFFFFu) | (u3.w << 16) };
    *(u32x4*)&h_lds[l * 16] = w0;
    *(u32x4*)&h_lds[l * 16 + 8] = w1;

    // gates via 32 chained MFMAs: B = h[k0*32 + kb*8 .. +8] broadcast cols
    const _Float16* hb = &h_lds[kb * 8];
    f32x4 acc0 = {0.f, 0.f, 0.f, 0.f}, acc1 = {0.f, 0.f, 0.f, 0.f};
#pragma unroll
    for (int k0 = 0; k0 < 32; k0 += 2) {
      f16x8 b0 = *(const f16x8*)(hb + k0 * 32);
      f16x8 b1 = *(const f16x8*)(hb + (k0 + 1) * 32);
      acc0 = MFMA16(afrag[k0], b0, acc0);
      acc1 = MFMA16(afrag[k0 + 1], b1, acc1);
    }
    f32x4 gsum = acc0 + acc1;

    // every lane finalizes entry e0+kb (16-way redundant, deterministic)
    float si = fast_sig(gsum[0] + xpv0);
    float sf = fast_sig(gsum[1] + xpv1);
    float tg = fast_tanh(gsum[2] + xpv2);
    float so = fast_sig(gsum[3] + xpv3);
    cst = sf * cst + si * tg;
    float hval = so * fast_tanh(cst);

    // publish: 2 u64 (4 entries) x 4 replicas via atomicExch (lanes 0-7)
    unsigned pk = ((unsigned)s << 16) |
                  (unsigned)__half_as_ushort(__float2half(hval));
    unsigned f0 = (unsigned)__shfl((int)pk, 0);
    unsigned f1 = (unsigned)__shfl((int)pk, 16);
    unsigned f2 = (unsigned)__shfl((int)pk, 32);
    unsigned f3 = (unsigned)__shfl((int)pk, 48);
    if (l < 8) {
      unsigned long long val = (l & 1)
          ? ((unsigned long long)f2 | ((unsigned long long)f3 << 32))
          : ((unsigned long long)f0 | ((unsigned long long)f1 << 32));
      unsigned long long* dst =
          (unsigned long long*)((char*)slots + (l >> 1) * RSTRIDE_B + (s & 1) * 4096)
          + (e0 >> 1) + (l & 1);
      atomicExch(dst, val);
    }
    if (m == 0) hs[(size_t)t * HID + e0 + kb] = hval;  // fp32 history
  }
}

// tag_space = hs @ W_out^T + b_out; log_softmax per row. 8 rows per WG, 1 wave.
__global__ __launch_bounds__(64) void out_kernel(const float* __restrict__ hs,
                                                 const float* __restrict__ W_out,
                                                 const float* __restrict__ b_out,
                                                 float* __restrict__ out) {
  __shared__ float hl[8 * HID];
  const int l = threadIdx.x;
  const int b = blockIdx.x;
  const float* hr = hs + (size_t)b * 8 * HID;
#pragma unroll
  for (int jj = 0; jj < 32; jj++) {
    int f4 = l + 64 * jj;
    ((float4*)hl)[f4] = ((const float4*)hr)[f4];
  }
  __syncthreads();
  float acc[8];
#pragma unroll
  for (int r = 0; r < 8; r++) acc[r] = 0.f;
  const float* wrow = W_out + (size_t)l * HID;
  for (int e = 0; e < HID; e += 4) {
    float4 wv = *(const float4*)(wrow + e);
#pragma unroll
    for (int r = 0; r < 8; r++) {
      float4 hv = *(const float4*)&hl[r * HID + e];
      acc[r] += wv.x * hv.x + wv.y * hv.y + wv.z * hv.z + wv.w * hv.w;
    }
  }
  const float bo = b_out[l];
#pragma unroll
  for (int r = 0; r < 8; r++) {
    float v = acc[r] + bo;
    float mx = v;
#pragma unroll
    for (int mm = 32; mm >= 1; mm >>= 1) mx = fmaxf(mx, __shfl_xor(mx, mm));
    float ex = __expf(v - mx);
    float sm = ex;
#pragma unroll
    for (int mm = 32; mm >= 1; mm >>= 1) sm += __shfl_xor(sm, mm);
    out[(size_t)(b * 8 + r) * NTAGS + l] = v - mx - __logf(sm);
  }
}

extern "C" void kernel_launch(void* const* d_in, const int* in_sizes, int n_in,
                              void* d_out, int out_size, void* d_ws, size_t ws_size,
                              hipStream_t stream) {
  const int* sent = (const int*)d_in[0];
  const float* emb = (const float*)d_in[1];
  const float* W_ih = (const float*)d_in[2];
  const float* W_hh = (const float*)d_in[3];
  const float* b_ih = (const float*)d_in[4];
  const float* b_hh = (const float*)d_in[5];
  const float* W_out = (const float*)d_in[6];
  const float* b_out = (const float*)d_in[7];
  float* out = (float*)d_out;

  char* ws = (char*)d_ws;
  float* xp = (float*)ws;                                    // 64 MB
  float* hs = (float*)(ws + ((size_t)64 << 20));             // 16 MB
  unsigned* slots = (unsigned*)(ws + ((size_t)80 << 20));    // 4 * 8448 B
  float* bsum = (float*)(ws + ((size_t)80 << 20) + 131072);  // 16 KB

  prep_kernel<<<16, 256, 0, stream>>>(b_ih, b_hh, bsum, slots);
  dim3 grid(G4H / 64, T_LEN / 64);
  xproj_gemm<<<grid, 256, 0, stream>>>(sent, emb, W_ih, bsum, xp);
  lstm_scan<<<NWG_SCAN, 64, 0, stream>>>(W_hh, xp, slots, hs);
  out_kernel<<<512, 64, 0, stream>>>(hs, W_out, b_out, out);
}